// Round 4
// baseline (301.743 us; speedup 1.0000x reference)
//
#include <hip/hip_runtime.h>
#include <math.h>

#define KD 5
#define NN 60000
#define EE 360000
#define NP1 30000
#define EE2 180000
#define NP2 15000
#define GG 60

// conv2 bucketing
#define PADMAX (EE2 + 25 * 64)          // 181600 worst-case padded bucket total
#define BWAVES ((PADMAX + 63) / 64)     // 2838 waves
#define CBLK ((BWAVES + 3) / 4)         // 710 blocks of 4 waves

// pool2/global-pool partials
#define PB2 120
#define CPB2 125   // ceil(NP2 / PB2)

// ---------- helpers ----------

__device__ __forceinline__ unsigned fkey(float f) {
    unsigned u = __float_as_uint(f);
    return (u & 0x80000000u) ? ~u : (u | 0x80000000u);
}
__device__ __forceinline__ float fkey_inv(unsigned k) {
    unsigned u = (k & 0x80000000u) ? (k ^ 0x80000000u) : ~k;
    return __uint_as_float(u);
}

__device__ __forceinline__ void spline_basis(float p0, float p1, int* idx, float* w) {
    float v0 = p0 * 4.0f, v1 = p1 * 4.0f;
    float fl0 = floorf(v0), fl1 = floorf(v1);
    int i0 = min(max((int)fl0, 0), KD - 1);
    int i1 = min(max((int)fl1, 0), KD - 1);
    float fr0 = v0 - fl0, fr1 = v1 - fl1;
    int c = 0;
#pragma unroll
    for (int s0 = 0; s0 < 2; ++s0) {
#pragma unroll
        for (int s1 = 0; s1 < 2; ++s1) {
            int ix = min(i0 + s0, KD - 1);
            int iy = min(i1 + s1, KD - 1);
            float w0 = s0 ? fr0 : 1.0f - fr0;
            float w1 = s1 ? fr1 : 1.0f - fr1;
            idx[c] = ix + KD * iy;
            w[c] = w0 * w1;
            ++c;
        }
    }
}

// cell + basis weights from RAW cartesian attr (applies the scale transform
// inline, bit-identical to attr2 = c/(2s)+0.5 then v = attr*4)
__device__ __forceinline__ void cell_basis(float c0, float c1, float s,
                                           int& cell, float4& w4) {
    float p0 = c0 / (2.0f * s) + 0.5f;
    float p1 = c1 / (2.0f * s) + 0.5f;
    float v0 = p0 * 4.0f, v1 = p1 * 4.0f;
    float fl0 = floorf(v0), fl1 = floorf(v1);
    int i0 = min(max((int)fl0, 0), KD - 1);
    int i1 = min(max((int)fl1, 0), KD - 1);
    float fr0 = v0 - fl0, fr1 = v1 - fl1;
    cell = i0 + 5 * i1;
    w4.x = (1.0f - fr0) * (1.0f - fr1);  // k=0 (s0=0,s1=0)
    w4.y = (1.0f - fr0) * fr1;           // k=1 (s0=0,s1=1)
    w4.z = fr0 * (1.0f - fr1);           // k=2 (s0=1,s1=0)
    w4.w = fr0 * fr1;                    // k=3 (s0=1,s1=1)
}

__device__ __forceinline__ float elu1(float v) {
    return v > 0.0f ? v : expm1f(v);
}

// ---------- conv1 ----------

__global__ void conv1_edge(const float* __restrict__ x, const float* __restrict__ ea,
                           const int* __restrict__ ei, const float* __restrict__ W1,
                           float* __restrict__ agg1, float* __restrict__ cnt1) {
    int gid = blockIdx.x * blockDim.x + threadIdx.x;
    if (gid >= EE * 32) return;
    int e = gid >> 5, f = gid & 31;
    int src = ei[e], dst = ei[EE + e];
    int idx[4]; float w[4];
    spline_basis(ea[2 * e], ea[2 * e + 1], idx, w);
    float coeff = 0.0f;
#pragma unroll
    for (int k = 0; k < 4; ++k) coeff += w[k] * W1[idx[k] * 32 + f];
    atomicAdd(&agg1[dst * 32 + f], x[src] * coeff);
    if (f == 0) atomicAdd(&cnt1[dst], 1.0f);
}

__global__ void conv1_fin(const float* __restrict__ x, const float* __restrict__ root1,
                          const float* __restrict__ bias1, const float* __restrict__ cnt1,
                          float* __restrict__ agg1) {
    int gid = blockIdx.x * blockDim.x + threadIdx.x;
    if (gid >= NN * 32) return;
    int n = gid >> 5, f = gid & 31;
    float v = agg1[gid] / fmaxf(cnt1[n], 1.0f) + x[n] * root1[f] + bias1[f];
    agg1[gid] = elu1(v);
}

// ---------- pool1 ----------

__global__ void pool1(const float* __restrict__ h, const float* __restrict__ pos,
                      const int* __restrict__ batch, const int* __restrict__ cl1,
                      unsigned* __restrict__ x1key, int* __restrict__ ccnt1,
                      float* __restrict__ pos1, int* __restrict__ batch1) {
    int gid = blockIdx.x * blockDim.x + threadIdx.x;
    if (gid >= NN * 32) return;
    int n = gid >> 5, f = gid & 31;
    int c = cl1[n];
    atomicMax(&x1key[c * 32 + f], fkey(h[gid]));
    if (f == 0) {
        atomicAdd(&ccnt1[c], 1);
        atomicAdd(&pos1[c * 2], pos[n * 2]);
        atomicAdd(&pos1[c * 2 + 1], pos[n * 2 + 1]);
        atomicMax(&batch1[c], batch[n]);
    }
}

__global__ void pool1_fin(unsigned* __restrict__ x1key, const int* __restrict__ ccnt1,
                          float* __restrict__ pos1) {
    int gid = blockIdx.x * blockDim.x + threadIdx.x;
    if (gid >= NP1 * 32) return;
    int c = gid >> 5, f = gid & 31;
    int cnt = ccnt1[c];
    float v = cnt > 0 ? fkey_inv(x1key[gid]) : 0.0f;
    ((float*)x1key)[gid] = v;
    if (f < 2) pos1[c * 2 + f] = pos1[c * 2 + f] / fmaxf((float)cnt, 1.0f);
}

// ---------- cartesian (stores RAW cart; also counts cnt2 per dst) ----------

__global__ void cart_k(const float* __restrict__ pos1, const int* __restrict__ ei2,
                       float* __restrict__ cart, unsigned* __restrict__ scaleb,
                       float* __restrict__ cnt2) {
    int e = blockIdx.x * blockDim.x + threadIdx.x;
    float m = 0.0f;
    if (e < EE2) {
        int s = ei2[e], d = ei2[EE2 + e];
        float c0 = pos1[d * 2] - pos1[s * 2];
        float c1 = pos1[d * 2 + 1] - pos1[s * 2 + 1];
        cart[e * 2] = c0;
        cart[e * 2 + 1] = c1;
        m = fmaxf(fabsf(c0), fabsf(c1));
        atomicAdd(&cnt2[d], 1.0f);
    }
#pragma unroll
    for (int off = 32; off > 0; off >>= 1) m = fmaxf(m, __shfl_down(m, off));
    if ((threadIdx.x & 63) == 0) atomicMax(scaleb, __float_as_uint(m));
}

// ---------- conv2 bucketing by B-spline cell ----------

__global__ void bucket_count(const float* __restrict__ cart,
                             const unsigned* __restrict__ scaleb,
                             int* __restrict__ ccount) {
    __shared__ int lc[25];
    int t = threadIdx.x;
    if (t < 25) lc[t] = 0;
    __syncthreads();
    int e = blockIdx.x * blockDim.x + t;
    if (e < EE2) {
        float s = fmaxf(__uint_as_float(*scaleb), 1e-12f);
        int cell; float4 w4;
        cell_basis(cart[2 * e], cart[2 * e + 1], s, cell, w4);
        atomicAdd(&lc[cell], 1);
    }
    __syncthreads();
    if (t < 25 && lc[t] > 0) atomicAdd(&ccount[t], lc[t]);
}

__global__ void bucket_scan(const int* __restrict__ ccount, int* __restrict__ aoff,
                            int* __restrict__ gcursor) {
    if (blockIdx.x == 0 && threadIdx.x == 0) {
        int acc = 0;
        for (int c = 0; c < 25; ++c) {
            aoff[c] = acc;
            gcursor[c] = acc;
            acc += (ccount[c] + 63) & ~63;   // 64-align each bucket
        }
        aoff[25] = acc;
    }
}

__global__ void bucket_scatter(const float* __restrict__ cart,
                               const unsigned* __restrict__ scaleb,
                               const int* __restrict__ ei2,
                               int* __restrict__ gcursor,
                               int* __restrict__ bsrc, int* __restrict__ bdst,
                               float4* __restrict__ bw) {
    __shared__ int lc[25], lb[25];
    int t = threadIdx.x;
    if (t < 25) lc[t] = 0;
    __syncthreads();
    int e = blockIdx.x * blockDim.x + t;
    bool valid = e < EE2;
    int cell = 0, rank = 0;
    float4 w4 = make_float4(0.f, 0.f, 0.f, 0.f);
    if (valid) {
        float s = fmaxf(__uint_as_float(*scaleb), 1e-12f);
        cell_basis(cart[2 * e], cart[2 * e + 1], s, cell, w4);
        rank = atomicAdd(&lc[cell], 1);
    }
    __syncthreads();
    if (t < 25) lb[t] = lc[t] > 0 ? atomicAdd(&gcursor[t], lc[t]) : 0;
    __syncthreads();
    if (valid) {
        int pos = lb[cell] + rank;
        bsrc[pos] = ei2[e];
        bdst[pos] = ei2[EE2 + e];
        bw[pos] = w4;
    }
}

// ---------- conv2: register-stationary weights, one cell per wave ----------

__global__ __launch_bounds__(256) void conv2_reg(const int* __restrict__ bsrc,
                                                 const int* __restrict__ bdst,
                                                 const float4* __restrict__ bw,
                                                 const int* __restrict__ aoff,
                                                 const float* __restrict__ x1,
                                                 const float* __restrict__ W2,
                                                 float* __restrict__ agg2) {
    __shared__ int soff[26];
    if (threadIdx.x < 26) soff[threadIdx.x] = aoff[threadIdx.x];
    __syncthreads();
    const int wave = (blockIdx.x << 2) + (threadIdx.x >> 6);
    const int lane = threadIdx.x & 63;
    const int base = wave << 6;
    if (base >= soff[25]) return;
    int cell = 0;
#pragma unroll
    for (int c = 1; c < 25; ++c)
        if (base >= soff[c]) cell = c;
    const int cx = cell % 5, cy = cell / 5;

    // cell's 4-slot weight block in registers: lane = fout, wreg[k][fi]
    float wreg[4][32];
#pragma unroll
    for (int k = 0; k < 4; ++k) {
        int sl = min(cx + (k >> 1), 4) + 5 * min(cy + (k & 1), 4);
        const float* wp = W2 + sl * 2048 + lane;
#pragma unroll
        for (int fi = 0; fi < 32; ++fi) wreg[k][fi] = wp[fi * 64];
    }

    for (int i = 0; i < 64; ++i) {
        int e = base + i;
        int src = bsrc[e];           // same addr all lanes -> broadcast
        if (src < 0) continue;       // bucket padding
        int dst = bdst[e];
        float4 w4 = bw[e];
        const float4* xp = (const float4*)(x1 + src * 32);
        float4 xv[8];
#pragma unroll
        for (int g = 0; g < 8; ++g) xv[g] = xp[g];
        float acc[4];
#pragma unroll
        for (int k = 0; k < 4; ++k) {
            float a = 0.0f;
#pragma unroll
            for (int g = 0; g < 8; ++g) {
                a += xv[g].x * wreg[k][g * 4 + 0];
                a += xv[g].y * wreg[k][g * 4 + 1];
                a += xv[g].z * wreg[k][g * 4 + 2];
                a += xv[g].w * wreg[k][g * 4 + 3];
            }
            acc[k] = a;
        }
        float msg = w4.x * acc[0] + w4.y * acc[1] + w4.z * acc[2] + w4.w * acc[3];
        atomicAdd(&agg2[dst * 64 + lane], msg);
    }
}

__global__ void conv2_fin(const float* __restrict__ x1, const float* __restrict__ root2,
                          const float* __restrict__ bias2, const float* __restrict__ cnt2,
                          float* __restrict__ agg2) {
    int gid = blockIdx.x * blockDim.x + threadIdx.x;
    if (gid >= NP1 * 64) return;
    int n = gid >> 6, f = gid & 63;
    float r = 0.0f;
    const float* xs = x1 + n * 32;
#pragma unroll
    for (int i = 0; i < 32; ++i) r += xs[i] * root2[i * 64 + f];
    float v = agg2[gid] / fmaxf(cnt2[n], 1.0f) + r + bias2[f];
    agg2[gid] = elu1(v);
}

// ---------- pool2 ----------

__global__ void pool2(const float* __restrict__ h2, const int* __restrict__ batch1,
                      const int* __restrict__ cl2, unsigned* __restrict__ x2key,
                      int* __restrict__ ccnt2, int* __restrict__ batch2) {
    int gid = blockIdx.x * blockDim.x + threadIdx.x;
    if (gid >= NP1 * 64) return;
    int n = gid >> 6, f = gid & 63;
    int c = cl2[n];
    atomicMax(&x2key[c * 64 + f], fkey(h2[gid]));
    if (f == 0) {
        atomicAdd(&ccnt2[c], 1);
        atomicMax(&batch2[c], batch1[n]);
    }
}

// ---------- global mean pool: per-block LDS partials, no global atomics ----------

__global__ __launch_bounds__(256) void pool2_part(const unsigned* __restrict__ x2key,
                                                  const int* __restrict__ ccnt2,
                                                  const int* __restrict__ batch2,
                                                  float* __restrict__ partial,
                                                  float* __restrict__ pcnt) {
    __shared__ float gs[GG * 64 + GG];
    const int t = threadIdx.x;
    for (int i = t; i < GG * 64 + GG; i += 256) gs[i] = 0.0f;
    __syncthreads();
    const int lane = t & 63, wv = t >> 6;
    const int c0 = blockIdx.x * CPB2;
    const int c1 = min(c0 + CPB2, NP2);
    for (int c = c0 + wv; c < c1; c += 4) {
        int cnt = ccnt2[c];
        int g = batch2[c];
        float v = cnt > 0 ? fkey_inv(x2key[c * 64 + lane]) : 0.0f;
        atomicAdd(&gs[g * 64 + lane], v);
        if (lane == 0) atomicAdd(&gs[GG * 64 + g], 1.0f);
    }
    __syncthreads();
    float* pb = partial + (size_t)blockIdx.x * (GG * 64);
    for (int i = t; i < GG * 64; i += 256) pb[i] = gs[i];
    if (t < GG) pcnt[blockIdx.x * GG + t] = gs[GG * 64 + t];
}

// ---------- fused partial-reduce + head (one block per graph) ----------

__global__ __launch_bounds__(128) void gpool_head(const float* __restrict__ partial,
                                                  const float* __restrict__ pcnt,
                                                  const float* __restrict__ fc1w,
                                                  const float* __restrict__ fc1b,
                                                  const float* __restrict__ fc2w,
                                                  const float* __restrict__ fc2b,
                                                  float* __restrict__ out) {
    const int g = blockIdx.x;
    const int t = threadIdx.x;  // 128
    __shared__ float red[128];
    __shared__ float acc2[128];
    __shared__ float gm[64];
    __shared__ float h3[128];
    __shared__ float lg[3];

    red[t] = (t < PB2) ? pcnt[t * GG + g] : 0.0f;
    __syncthreads();
    for (int s = 64; s > 0; s >>= 1) {
        if (t < s) red[t] += red[t + s];
        __syncthreads();
    }

    const int f = t & 63, h = t >> 6;
    float acc = 0.0f;
    for (int b = h * (PB2 / 2); b < (h + 1) * (PB2 / 2); ++b)
        acc += partial[(size_t)b * (GG * 64) + g * 64 + f];
    acc2[t] = acc;
    __syncthreads();
    if (t < 64) gm[t] = (acc2[t] + acc2[t + 64]) / fmaxf(red[0], 1.0f);
    __syncthreads();

    float a = fc1b[t];
#pragma unroll
    for (int i = 0; i < 64; ++i) a += gm[i] * fc1w[i * 128 + t];
    h3[t] = elu1(a);
    __syncthreads();
    if (t < 3) {
        float a2 = fc2b[t];
#pragma unroll
        for (int i = 0; i < 128; ++i) a2 += h3[i] * fc2w[i * 3 + t];
        lg[t] = a2;
    }
    __syncthreads();
    if (t == 0) {
        float m = fmaxf(lg[0], fmaxf(lg[1], lg[2]));
        float s = expf(lg[0] - m) + expf(lg[1] - m) + expf(lg[2] - m);
        float lse = m + logf(s);
        out[g * 3 + 0] = lg[0] - lse;
        out[g * 3 + 1] = lg[1] - lse;
        out[g * 3 + 2] = lg[2] - lse;
    }
}

// ---------- launcher ----------

extern "C" void kernel_launch(void* const* d_in, const int* in_sizes, int n_in,
                              void* d_out, int out_size, void* d_ws, size_t ws_size,
                              hipStream_t stream) {
    const float* x     = (const float*)d_in[0];
    const float* pos   = (const float*)d_in[1];
    const float* eattr = (const float*)d_in[2];
    const int*   ei    = (const int*)d_in[3];
    const int*   batch = (const int*)d_in[4];
    const int*   cl1   = (const int*)d_in[5];
    const int*   ei2   = (const int*)d_in[6];
    const int*   cl2   = (const int*)d_in[7];
    const float* W1    = (const float*)d_in[8];
    const float* root1 = (const float*)d_in[9];
    const float* bias1 = (const float*)d_in[10];
    const float* W2    = (const float*)d_in[11];
    const float* root2 = (const float*)d_in[12];
    const float* bias2 = (const float*)d_in[13];
    const float* fc1w  = (const float*)d_in[14];
    const float* fc1b  = (const float*)d_in[15];
    const float* fc2w  = (const float*)d_in[16];
    const float* fc2b  = (const float*)d_in[17];
    float* out = (float*)d_out;

    char* p = (char*)d_ws;
    auto carve = [&](size_t bytes) {
        char* r = p;
        p += (bytes + 255) & ~(size_t)255;
        return r;
    };
    float*    agg1    = (float*)carve((size_t)NN * 32 * 4);
    float*    cnt1    = (float*)carve((size_t)NN * 4);
    unsigned* x1key   = (unsigned*)carve((size_t)NP1 * 32 * 4);  // becomes float x1 in-place
    int*      ccnt1   = (int*)carve((size_t)NP1 * 4);
    float*    pos1    = (float*)carve((size_t)NP1 * 2 * 4);
    int*      batch1  = (int*)carve((size_t)NP1 * 4);
    unsigned* scaleb  = (unsigned*)carve(4);
    float*    cart    = (float*)carve((size_t)EE2 * 2 * 4);
    float*    agg2    = (float*)carve((size_t)NP1 * 64 * 4);
    float*    cnt2    = (float*)carve((size_t)NP1 * 4);
    unsigned* x2key   = (unsigned*)carve((size_t)NP2 * 64 * 4);
    int*      ccnt2   = (int*)carve((size_t)NP2 * 4);
    int*      batch2  = (int*)carve((size_t)NP2 * 4);
    float*    partial = (float*)carve((size_t)PB2 * GG * 64 * 4);
    float*    pcnt    = (float*)carve((size_t)PB2 * GG * 4);
    int*      ccount  = (int*)carve(25 * 4);
    int*      aoff    = (int*)carve(26 * 4);
    int*      gcursor = (int*)carve(25 * 4);
    size_t used = (size_t)(p - (char*)d_ws);

    // bucket arrays alias agg1 (dead after pool1): 4.36MB <= 7.68MB
    int*    bsrc = (int*)agg1;
    int*    bdst = bsrc + PADMAX;
    float4* bw   = (float4*)(bdst + PADMAX);

    hipMemsetAsync(d_ws, 0, used, stream);

    const int B = 256;
    conv1_edge<<<(EE * 32 + B - 1) / B, B, 0, stream>>>(x, eattr, ei, W1, agg1, cnt1);
    conv1_fin<<<(NN * 32 + B - 1) / B, B, 0, stream>>>(x, root1, bias1, cnt1, agg1);
    pool1<<<(NN * 32 + B - 1) / B, B, 0, stream>>>(agg1, pos, batch, cl1, x1key, ccnt1, pos1, batch1);
    pool1_fin<<<(NP1 * 32 + B - 1) / B, B, 0, stream>>>(x1key, ccnt1, pos1);
    // agg1 dead from here; mark bucket padding entries invalid
    hipMemsetAsync(bsrc, 0xFF, (size_t)PADMAX * 4, stream);
    cart_k<<<(EE2 + B - 1) / B, B, 0, stream>>>(pos1, ei2, cart, scaleb, cnt2);
    bucket_count<<<(EE2 + B - 1) / B, B, 0, stream>>>(cart, scaleb, ccount);
    bucket_scan<<<1, 64, 0, stream>>>(ccount, aoff, gcursor);
    bucket_scatter<<<(EE2 + B - 1) / B, B, 0, stream>>>(cart, scaleb, ei2, gcursor, bsrc, bdst, bw);
    conv2_reg<<<CBLK, 256, 0, stream>>>(bsrc, bdst, bw, aoff, (const float*)x1key, W2, agg2);
    conv2_fin<<<(NP1 * 64 + B - 1) / B, B, 0, stream>>>((const float*)x1key, root2, bias2, cnt2, agg2);
    pool2<<<(NP1 * 64 + B - 1) / B, B, 0, stream>>>(agg2, batch1, cl2, x2key, ccnt2, batch2);
    pool2_part<<<PB2, 256, 0, stream>>>(x2key, ccnt2, batch2, partial, pcnt);
    gpool_head<<<GG, 128, 0, stream>>>(partial, pcnt, fc1w, fc1b, fc2w, fc2b, out);
}

// Round 5
// 288.551 us; speedup vs baseline: 1.0457x; 1.0457x over previous
//
#include <hip/hip_runtime.h>
#include <math.h>

#define KD 5
#define NN 60000
#define EE 360000
#define NP1 30000
#define EE2 180000
#define NP2 15000
#define GG 60

// conv2 bucketing
#define PADMAX (EE2 + 25 * 64)          // 181600 worst-case padded bucket total
#define BWAVES ((PADMAX + 63) / 64)     // 2838 waves
#define CBLK ((BWAVES + 3) / 4)         // 710 blocks of 4 waves

// pool2/global-pool partials
#define PB2 120
#define CPB2 125   // ceil(NP2 / PB2)

// ---------- helpers ----------

__device__ __forceinline__ unsigned fkey(float f) {
    unsigned u = __float_as_uint(f);
    return (u & 0x80000000u) ? ~u : (u | 0x80000000u);
}
__device__ __forceinline__ float fkey_inv(unsigned k) {
    unsigned u = (k & 0x80000000u) ? (k ^ 0x80000000u) : ~k;
    return __uint_as_float(u);
}

__device__ __forceinline__ void spline_basis(float p0, float p1, int* idx, float* w) {
    float v0 = p0 * 4.0f, v1 = p1 * 4.0f;
    float fl0 = floorf(v0), fl1 = floorf(v1);
    int i0 = min(max((int)fl0, 0), KD - 1);
    int i1 = min(max((int)fl1, 0), KD - 1);
    float fr0 = v0 - fl0, fr1 = v1 - fl1;
    int c = 0;
#pragma unroll
    for (int s0 = 0; s0 < 2; ++s0) {
#pragma unroll
        for (int s1 = 0; s1 < 2; ++s1) {
            int ix = min(i0 + s0, KD - 1);
            int iy = min(i1 + s1, KD - 1);
            float w0 = s0 ? fr0 : 1.0f - fr0;
            float w1 = s1 ? fr1 : 1.0f - fr1;
            idx[c] = ix + KD * iy;
            w[c] = w0 * w1;
            ++c;
        }
    }
}

// cell + basis weights from RAW cartesian attr (applies the scale transform
// inline, bit-identical to attr2 = c/(2s)+0.5 then v = attr*4)
__device__ __forceinline__ void cell_basis(float c0, float c1, float s,
                                           int& cell, float4& w4) {
    float p0 = c0 / (2.0f * s) + 0.5f;
    float p1 = c1 / (2.0f * s) + 0.5f;
    float v0 = p0 * 4.0f, v1 = p1 * 4.0f;
    float fl0 = floorf(v0), fl1 = floorf(v1);
    int i0 = min(max((int)fl0, 0), KD - 1);
    int i1 = min(max((int)fl1, 0), KD - 1);
    float fr0 = v0 - fl0, fr1 = v1 - fl1;
    cell = i0 + 5 * i1;
    w4.x = (1.0f - fr0) * (1.0f - fr1);  // k=0 (s0=0,s1=0)
    w4.y = (1.0f - fr0) * fr1;           // k=1 (s0=0,s1=1)
    w4.z = fr0 * (1.0f - fr1);           // k=2 (s0=1,s1=0)
    w4.w = fr0 * fr1;                    // k=3 (s0=1,s1=1)
}

__device__ __forceinline__ float elu1(float v) {
    return v > 0.0f ? v : expm1f(v);
}

// ---------- conv1 ----------

__global__ void conv1_edge(const float* __restrict__ x, const float* __restrict__ ea,
                           const int* __restrict__ ei, const float* __restrict__ W1,
                           float* __restrict__ agg1, float* __restrict__ cnt1) {
    int gid = blockIdx.x * blockDim.x + threadIdx.x;
    if (gid >= EE * 32) return;
    int e = gid >> 5, f = gid & 31;
    int src = ei[e], dst = ei[EE + e];
    int idx[4]; float w[4];
    spline_basis(ea[2 * e], ea[2 * e + 1], idx, w);
    float coeff = 0.0f;
#pragma unroll
    for (int k = 0; k < 4; ++k) coeff += w[k] * W1[idx[k] * 32 + f];
    atomicAdd(&agg1[dst * 32 + f], x[src] * coeff);
    if (f == 0) atomicAdd(&cnt1[dst], 1.0f);
}

// ---------- conv1 finish + pool1 (fused: same geometry, h kept in-register) ----------

__global__ void conv1fin_pool1(const float* __restrict__ x, const float* __restrict__ root1,
                               const float* __restrict__ bias1, const float* __restrict__ cnt1,
                               const float* __restrict__ agg1, const float* __restrict__ pos,
                               const int* __restrict__ batch, const int* __restrict__ cl1,
                               unsigned* __restrict__ x1key, int* __restrict__ ccnt1,
                               float* __restrict__ pos1, int* __restrict__ batch1) {
    int gid = blockIdx.x * blockDim.x + threadIdx.x;
    if (gid >= NN * 32) return;
    int n = gid >> 5, f = gid & 31;
    float v = elu1(agg1[gid] / fmaxf(cnt1[n], 1.0f) + x[n] * root1[f] + bias1[f]);
    int c = cl1[n];
    atomicMax(&x1key[c * 32 + f], fkey(v));
    if (f == 0) {
        atomicAdd(&ccnt1[c], 1);
        atomicAdd(&pos1[c * 2], pos[n * 2]);
        atomicAdd(&pos1[c * 2 + 1], pos[n * 2 + 1]);
        atomicMax(&batch1[c], batch[n]);
    }
}

__global__ void pool1_fin(unsigned* __restrict__ x1key, const int* __restrict__ ccnt1,
                          float* __restrict__ pos1) {
    int gid = blockIdx.x * blockDim.x + threadIdx.x;
    if (gid >= NP1 * 32) return;
    int c = gid >> 5, f = gid & 31;
    int cnt = ccnt1[c];
    float v = cnt > 0 ? fkey_inv(x1key[gid]) : 0.0f;
    ((float*)x1key)[gid] = v;
    if (f < 2) pos1[c * 2 + f] = pos1[c * 2 + f] / fmaxf((float)cnt, 1.0f);
}

// ---------- cartesian (stores RAW cart; also counts cnt2 per dst) ----------

__global__ void cart_k(const float* __restrict__ pos1, const int* __restrict__ ei2,
                       float* __restrict__ cart, unsigned* __restrict__ scaleb,
                       float* __restrict__ cnt2) {
    int e = blockIdx.x * blockDim.x + threadIdx.x;
    float m = 0.0f;
    if (e < EE2) {
        int s = ei2[e], d = ei2[EE2 + e];
        float c0 = pos1[d * 2] - pos1[s * 2];
        float c1 = pos1[d * 2 + 1] - pos1[s * 2 + 1];
        cart[e * 2] = c0;
        cart[e * 2 + 1] = c1;
        m = fmaxf(fabsf(c0), fabsf(c1));
        atomicAdd(&cnt2[d], 1.0f);
    }
#pragma unroll
    for (int off = 32; off > 0; off >>= 1) m = fmaxf(m, __shfl_down(m, off));
    if ((threadIdx.x & 63) == 0) atomicMax(scaleb, __float_as_uint(m));
}

// ---------- conv2 bucketing by B-spline cell ----------

__global__ void bucket_count(const float* __restrict__ cart,
                             const unsigned* __restrict__ scaleb,
                             int* __restrict__ ccount) {
    __shared__ int lc[25];
    int t = threadIdx.x;
    if (t < 25) lc[t] = 0;
    __syncthreads();
    int e = blockIdx.x * blockDim.x + t;
    if (e < EE2) {
        float s = fmaxf(__uint_as_float(*scaleb), 1e-12f);
        int cell; float4 w4;
        cell_basis(cart[2 * e], cart[2 * e + 1], s, cell, w4);
        atomicAdd(&lc[cell], 1);
    }
    __syncthreads();
    if (t < 25 && lc[t] > 0) atomicAdd(&ccount[t], lc[t]);
}

__global__ void bucket_scan(const int* __restrict__ ccount, int* __restrict__ aoff,
                            int* __restrict__ gcursor) {
    if (blockIdx.x == 0 && threadIdx.x == 0) {
        int acc = 0;
        for (int c = 0; c < 25; ++c) {
            aoff[c] = acc;
            gcursor[c] = acc;
            acc += (ccount[c] + 63) & ~63;   // 64-align each bucket
        }
        aoff[25] = acc;
    }
}

__global__ void bucket_scatter(const float* __restrict__ cart,
                               const unsigned* __restrict__ scaleb,
                               const int* __restrict__ ei2,
                               int* __restrict__ gcursor,
                               int* __restrict__ bsrc, int* __restrict__ bdst,
                               float4* __restrict__ bw) {
    __shared__ int lc[25], lb[25];
    int t = threadIdx.x;
    if (t < 25) lc[t] = 0;
    __syncthreads();
    int e = blockIdx.x * blockDim.x + t;
    bool valid = e < EE2;
    int cell = 0, rank = 0;
    float4 w4 = make_float4(0.f, 0.f, 0.f, 0.f);
    if (valid) {
        float s = fmaxf(__uint_as_float(*scaleb), 1e-12f);
        cell_basis(cart[2 * e], cart[2 * e + 1], s, cell, w4);
        rank = atomicAdd(&lc[cell], 1);
    }
    __syncthreads();
    if (t < 25) lb[t] = lc[t] > 0 ? atomicAdd(&gcursor[t], lc[t]) : 0;
    __syncthreads();
    if (valid) {
        int pos = lb[cell] + rank;
        bsrc[pos] = ei2[e];
        bdst[pos] = ei2[EE2 + e];
        bw[pos] = w4;
    }
}

// ---------- conv2: register-stationary weights, one cell per wave ----------
// __launch_bounds__(256, 1): allow ~500 VGPR so wreg[4][32] (128 regs) stays
// register-resident. R4's default heuristic capped at 84 VGPR -> demoted
// weights -> 87us. Verification signal: VGPR_Count should read ~190-220.

__global__ __launch_bounds__(256, 1) void conv2_reg(const int* __restrict__ bsrc,
                                                    const int* __restrict__ bdst,
                                                    const float4* __restrict__ bw,
                                                    const int* __restrict__ aoff,
                                                    const float* __restrict__ x1,
                                                    const float* __restrict__ W2,
                                                    float* __restrict__ agg2) {
    __shared__ int soff[26];
    if (threadIdx.x < 26) soff[threadIdx.x] = aoff[threadIdx.x];
    __syncthreads();
    const int wave = (blockIdx.x << 2) + (threadIdx.x >> 6);
    const int lane = threadIdx.x & 63;
    const int base = wave << 6;
    if (base >= soff[25]) return;
    int cell = 0;
#pragma unroll
    for (int c = 1; c < 25; ++c) cell += (base >= soff[c]) ? 1 : 0;
    const int cx = cell % 5, cy = cell / 5;

    // cell's 4-slot weight block in registers: lane = fout, wreg[k][fi]
    float wreg[4][32];
#pragma unroll
    for (int k = 0; k < 4; ++k) {
        int sl = min(cx + (k >> 1), 4) + 5 * min(cy + (k & 1), 4);
        const float* wp = W2 + sl * 2048 + lane;
#pragma unroll
        for (int fi = 0; fi < 32; ++fi) wreg[k][fi] = wp[fi * 64];
    }

    for (int i = 0; i < 64; ++i) {
        int e = base + i;
        int src = bsrc[e];           // same addr all lanes -> broadcast
        if (src < 0) continue;       // bucket padding
        int dst = bdst[e];
        float4 w4 = bw[e];
        const float4* xp = (const float4*)(x1 + src * 32);
        float4 xv[8];
#pragma unroll
        for (int g = 0; g < 8; ++g) xv[g] = xp[g];
        float acc[4];
#pragma unroll
        for (int k = 0; k < 4; ++k) {
            float a = 0.0f;
#pragma unroll
            for (int g = 0; g < 8; ++g) {
                a += xv[g].x * wreg[k][g * 4 + 0];
                a += xv[g].y * wreg[k][g * 4 + 1];
                a += xv[g].z * wreg[k][g * 4 + 2];
                a += xv[g].w * wreg[k][g * 4 + 3];
            }
            acc[k] = a;
        }
        float msg = w4.x * acc[0] + w4.y * acc[1] + w4.z * acc[2] + w4.w * acc[3];
        atomicAdd(&agg2[dst * 64 + lane], msg);
    }
}

// ---------- conv2 finish + pool2 (fused: same geometry) ----------

__global__ void conv2fin_pool2(const float* __restrict__ x1, const float* __restrict__ root2,
                               const float* __restrict__ bias2, const float* __restrict__ cnt2,
                               const float* __restrict__ agg2, const int* __restrict__ cl2,
                               const int* __restrict__ batch1, unsigned* __restrict__ x2key,
                               int* __restrict__ ccnt2, int* __restrict__ batch2) {
    int gid = blockIdx.x * blockDim.x + threadIdx.x;
    if (gid >= NP1 * 64) return;
    int n = gid >> 6, f = gid & 63;
    float r = 0.0f;
    const float* xs = x1 + n * 32;
#pragma unroll
    for (int i = 0; i < 32; ++i) r += xs[i] * root2[i * 64 + f];
    float v = elu1(agg2[gid] / fmaxf(cnt2[n], 1.0f) + r + bias2[f]);
    int c = cl2[n];
    atomicMax(&x2key[c * 64 + f], fkey(v));
    if (f == 0) {
        atomicAdd(&ccnt2[c], 1);
        atomicMax(&batch2[c], batch1[n]);
    }
}

// ---------- global mean pool: per-block LDS partials, no global atomics ----------

__global__ __launch_bounds__(256) void pool2_part(const unsigned* __restrict__ x2key,
                                                  const int* __restrict__ ccnt2,
                                                  const int* __restrict__ batch2,
                                                  float* __restrict__ partial,
                                                  float* __restrict__ pcnt) {
    __shared__ float gs[GG * 64 + GG];
    const int t = threadIdx.x;
    for (int i = t; i < GG * 64 + GG; i += 256) gs[i] = 0.0f;
    __syncthreads();
    const int lane = t & 63, wv = t >> 6;
    const int c0 = blockIdx.x * CPB2;
    const int c1 = min(c0 + CPB2, NP2);
    for (int c = c0 + wv; c < c1; c += 4) {
        int cnt = ccnt2[c];
        int g = batch2[c];
        float v = cnt > 0 ? fkey_inv(x2key[c * 64 + lane]) : 0.0f;
        atomicAdd(&gs[g * 64 + lane], v);
        if (lane == 0) atomicAdd(&gs[GG * 64 + g], 1.0f);
    }
    __syncthreads();
    float* pb = partial + (size_t)blockIdx.x * (GG * 64);
    for (int i = t; i < GG * 64; i += 256) pb[i] = gs[i];
    if (t < GG) pcnt[blockIdx.x * GG + t] = gs[GG * 64 + t];
}

// ---------- fused partial-reduce + head (one block per graph) ----------

__global__ __launch_bounds__(128) void gpool_head(const float* __restrict__ partial,
                                                  const float* __restrict__ pcnt,
                                                  const float* __restrict__ fc1w,
                                                  const float* __restrict__ fc1b,
                                                  const float* __restrict__ fc2w,
                                                  const float* __restrict__ fc2b,
                                                  float* __restrict__ out) {
    const int g = blockIdx.x;
    const int t = threadIdx.x;  // 128
    __shared__ float red[128];
    __shared__ float acc2[128];
    __shared__ float gm[64];
    __shared__ float h3[128];
    __shared__ float lg[3];

    red[t] = (t < PB2) ? pcnt[t * GG + g] : 0.0f;
    __syncthreads();
    for (int s = 64; s > 0; s >>= 1) {
        if (t < s) red[t] += red[t + s];
        __syncthreads();
    }

    const int f = t & 63, h = t >> 6;
    float acc = 0.0f;
    for (int b = h * (PB2 / 2); b < (h + 1) * (PB2 / 2); ++b)
        acc += partial[(size_t)b * (GG * 64) + g * 64 + f];
    acc2[t] = acc;
    __syncthreads();
    if (t < 64) gm[t] = (acc2[t] + acc2[t + 64]) / fmaxf(red[0], 1.0f);
    __syncthreads();

    float a = fc1b[t];
#pragma unroll
    for (int i = 0; i < 64; ++i) a += gm[i] * fc1w[i * 128 + t];
    h3[t] = elu1(a);
    __syncthreads();
    if (t < 3) {
        float a2 = fc2b[t];
#pragma unroll
        for (int i = 0; i < 128; ++i) a2 += h3[i] * fc2w[i * 3 + t];
        lg[t] = a2;
    }
    __syncthreads();
    if (t == 0) {
        float m = fmaxf(lg[0], fmaxf(lg[1], lg[2]));
        float s = expf(lg[0] - m) + expf(lg[1] - m) + expf(lg[2] - m);
        float lse = m + logf(s);
        out[g * 3 + 0] = lg[0] - lse;
        out[g * 3 + 1] = lg[1] - lse;
        out[g * 3 + 2] = lg[2] - lse;
    }
}

// ---------- launcher ----------

extern "C" void kernel_launch(void* const* d_in, const int* in_sizes, int n_in,
                              void* d_out, int out_size, void* d_ws, size_t ws_size,
                              hipStream_t stream) {
    const float* x     = (const float*)d_in[0];
    const float* pos   = (const float*)d_in[1];
    const float* eattr = (const float*)d_in[2];
    const int*   ei    = (const int*)d_in[3];
    const int*   batch = (const int*)d_in[4];
    const int*   cl1   = (const int*)d_in[5];
    const int*   ei2   = (const int*)d_in[6];
    const int*   cl2   = (const int*)d_in[7];
    const float* W1    = (const float*)d_in[8];
    const float* root1 = (const float*)d_in[9];
    const float* bias1 = (const float*)d_in[10];
    const float* W2    = (const float*)d_in[11];
    const float* root2 = (const float*)d_in[12];
    const float* bias2 = (const float*)d_in[13];
    const float* fc1w  = (const float*)d_in[14];
    const float* fc1b  = (const float*)d_in[15];
    const float* fc2w  = (const float*)d_in[16];
    const float* fc2b  = (const float*)d_in[17];
    float* out = (float*)d_out;

    char* p = (char*)d_ws;
    auto carve = [&](size_t bytes) {
        char* r = p;
        p += (bytes + 255) & ~(size_t)255;
        return r;
    };
    // regions needing zero-init first, fully-overwritten regions last
    float*    agg1    = (float*)carve((size_t)NN * 32 * 4);
    float*    cnt1    = (float*)carve((size_t)NN * 4);
    unsigned* x1key   = (unsigned*)carve((size_t)NP1 * 32 * 4);  // becomes float x1 in-place
    int*      ccnt1   = (int*)carve((size_t)NP1 * 4);
    float*    pos1    = (float*)carve((size_t)NP1 * 2 * 4);
    int*      batch1  = (int*)carve((size_t)NP1 * 4);
    unsigned* scaleb  = (unsigned*)carve(4);
    float*    agg2    = (float*)carve((size_t)NP1 * 64 * 4);
    float*    cnt2    = (float*)carve((size_t)NP1 * 4);
    unsigned* x2key   = (unsigned*)carve((size_t)NP2 * 64 * 4);
    int*      ccnt2   = (int*)carve((size_t)NP2 * 4);
    int*      batch2  = (int*)carve((size_t)NP2 * 4);
    int*      ccount  = (int*)carve(25 * 4);
    size_t zero_bytes = (size_t)(p - (char*)d_ws);
    int*      aoff    = (int*)carve(26 * 4);
    int*      gcursor = (int*)carve(25 * 4);
    float*    cart    = (float*)carve((size_t)EE2 * 2 * 4);
    float*    partial = (float*)carve((size_t)PB2 * GG * 64 * 4);
    float*    pcnt    = (float*)carve((size_t)PB2 * GG * 4);

    // bucket arrays alias agg1 (dead after conv1fin_pool1): 4.36MB <= 7.68MB
    int*    bsrc = (int*)agg1;
    int*    bdst = bsrc + PADMAX;
    float4* bw   = (float4*)(bdst + PADMAX);

    hipMemsetAsync(d_ws, 0, zero_bytes, stream);

    const int B = 256;
    conv1_edge<<<(EE * 32 + B - 1) / B, B, 0, stream>>>(x, eattr, ei, W1, agg1, cnt1);
    conv1fin_pool1<<<(NN * 32 + B - 1) / B, B, 0, stream>>>(x, root1, bias1, cnt1, agg1,
                                                            pos, batch, cl1, x1key, ccnt1,
                                                            pos1, batch1);
    pool1_fin<<<(NP1 * 32 + B - 1) / B, B, 0, stream>>>(x1key, ccnt1, pos1);
    // agg1 dead from here; mark bucket padding entries invalid
    hipMemsetAsync(bsrc, 0xFF, (size_t)PADMAX * 4, stream);
    cart_k<<<(EE2 + B - 1) / B, B, 0, stream>>>(pos1, ei2, cart, scaleb, cnt2);
    bucket_count<<<(EE2 + B - 1) / B, B, 0, stream>>>(cart, scaleb, ccount);
    bucket_scan<<<1, 64, 0, stream>>>(ccount, aoff, gcursor);
    bucket_scatter<<<(EE2 + B - 1) / B, B, 0, stream>>>(cart, scaleb, ei2, gcursor, bsrc, bdst, bw);
    conv2_reg<<<CBLK, 256, 0, stream>>>(bsrc, bdst, bw, aoff, (const float*)x1key, W2, agg2);
    conv2fin_pool2<<<(NP1 * 64 + B - 1) / B, B, 0, stream>>>((const float*)x1key, root2, bias2,
                                                             cnt2, agg2, cl2, batch1, x2key,
                                                             ccnt2, batch2);
    pool2_part<<<PB2, 256, 0, stream>>>(x2key, ccnt2, batch2, partial, pcnt);
    gpool_head<<<GG, 128, 0, stream>>>(partial, pcnt, fc1w, fc1b, fc2w, fc2b, out);
}